// Round 2
// baseline (645.099 us; speedup 1.0000x reference)
//
#include <hip/hip_runtime.h>

#define BATCH 8192
#define FEATURE_NUM 200
#define NUMERIC_SIZE 100
#define IN_STRIDE (FEATURE_NUM + NUMERIC_SIZE)  // 300
#define EMBED 64

// One wave (64 lanes) per batch row; lane = embedding dim e.
// Indices/numerics are preloaded into per-lane registers with 6 coalesced
// loads, then broadcast via v_readlane -> gathers have NO load->load
// dependency and can be kept ~16 deep in flight per wave.
__global__ __launch_bounds__(256, 8) void fm_layer_kernel(
    const float* __restrict__ inputs,      // (B, 300)
    const float* __restrict__ w_one_hot,   // (1e6, 1)
    const float* __restrict__ w_numeric,   // (100, 1)
    const float* __restrict__ v_one_hot,   // (1e6, 64)
    const float* __restrict__ v_numeric,   // (100, 64)
    const float* __restrict__ bias,        // (1,)
    float* __restrict__ out)               // (B, 1)
{
    const int lane = threadIdx.x & 63;
    const int wave = threadIdx.x >> 6;
    const int row  = blockIdx.x * 4 + wave;

    const float* in_row = inputs + (size_t)row * IN_STRIDE;

    // ---- preload this row's 200 indices into 4 regs (coalesced) ----
    int idxreg[4];
    #pragma unroll
    for (int k = 0; k < 4; ++k) {
        int j = lane + 64 * k;
        idxreg[k] = (j < FEATURE_NUM) ? (int)in_row[j] : 0;
    }
    // ---- preload 100 numerics into 2 regs (coalesced) ----
    float numreg[2];
    #pragma unroll
    for (int k = 0; k < 2; ++k) {
        int j = lane + 64 * k;
        numreg[k] = (j < NUMERIC_SIZE) ? in_row[FEATURE_NUM + j] : 0.f;
    }

    float fs  = 0.f;   // field_sum[lane]
    float fss = 0.f;   // field_sq_sum[lane]

    // ---- second-order one-hot gathers: 200 independent 256B row reads ----
    // idx comes from a register broadcast (readlane) -> no memory dependency;
    // full unroll lets the compiler batch many gathers per s_waitcnt.
    #pragma unroll
    for (int k = 0; k < 3; ++k) {
        #pragma unroll
        for (int s = 0; s < 64; ++s) {
            int idx = __builtin_amdgcn_readlane(idxreg[k], s);
            float v = v_one_hot[(size_t)idx * EMBED + lane];
            fs  += v;
            fss += v * v;
        }
    }
    #pragma unroll
    for (int s = 0; s < 8; ++s) {   // features 192..199
        int idx = __builtin_amdgcn_readlane(idxreg[3], s);
        float v = v_one_hot[(size_t)idx * EMBED + lane];
        fs  += v;
        fss += v * v;
    }

    // ---- second-order numeric part (v_numeric: 25.6 KB, L1/L2 resident) ----
    #pragma unroll
    for (int s = 0; s < 64; ++s) {
        float x  = __builtin_amdgcn_readlane(__float_as_int(numreg[0]), s) == 0
                   ? 0.f : 0.f;  // placeholder avoided; see below
        (void)x;
        break;
    }
    // (readlane returns int; go through bit-cast helpers)
    #pragma unroll
    for (int s = 0; s < 64; ++s) {
        float x  = __int_as_float(__builtin_amdgcn_readlane(__float_as_int(numreg[0]), s));
        float v  = v_numeric[s * EMBED + lane];
        float nv = x * v;
        fs  += nv;
        fss += nv * nv;
    }
    #pragma unroll
    for (int s = 0; s < 36; ++s) {  // numerics 64..99
        float x  = __int_as_float(__builtin_amdgcn_readlane(__float_as_int(numreg[1]), s));
        float v  = v_numeric[(64 + s) * EMBED + lane];
        float nv = x * v;
        fs  += nv;
        fss += nv * nv;
    }

    // ---- first-order: reuse preloaded regs; per-lane scattered 4B gathers ----
    float first = 0.f;
    #pragma unroll
    for (int k = 0; k < 4; ++k) {
        int j = lane + 64 * k;
        if (j < FEATURE_NUM) first += w_one_hot[idxreg[k]];
    }
    #pragma unroll
    for (int k = 0; k < 2; ++k) {
        int j = lane + 64 * k;
        if (j < NUMERIC_SIZE) first += numreg[k] * w_numeric[j];
    }

    // per-lane partial: first-order partial + FM identity term for e=lane
    float partial = first + 0.5f * (fs * fs - fss);

    // wave64 reduction
    #pragma unroll
    for (int off = 32; off > 0; off >>= 1)
        partial += __shfl_down(partial, off, 64);

    if (lane == 0) out[row] = partial + bias[0];
}

extern "C" void kernel_launch(void* const* d_in, const int* in_sizes, int n_in,
                              void* d_out, int out_size, void* d_ws, size_t ws_size,
                              hipStream_t stream) {
    const float* inputs    = (const float*)d_in[0];
    const float* w_one_hot = (const float*)d_in[1];
    const float* w_numeric = (const float*)d_in[2];
    const float* v_one_hot = (const float*)d_in[3];
    const float* v_numeric = (const float*)d_in[4];
    const float* bias      = (const float*)d_in[5];
    float* out = (float*)d_out;

    dim3 grid(BATCH / 4);   // 4 rows (waves) per 256-thread block
    dim3 block(256);
    fm_layer_kernel<<<grid, block, 0, stream>>>(
        inputs, w_one_hot, w_numeric, v_one_hot, v_numeric, bias, out);
}

// Round 3
// 374.913 us; speedup vs baseline: 1.7207x; 1.7207x over previous
//
#include <hip/hip_runtime.h>

#define BATCH 8192
#define FEATURE_NUM 200
#define NUMERIC_SIZE 100
#define IN_STRIDE (FEATURE_NUM + NUMERIC_SIZE)  // 300
#define EMBED 64
#define WAVES_PER_BLOCK 4

// One wave (64 lanes) per batch row; lane = embedding dim e.
// Row inputs staged once in LDS (idx pre-converted to int). Gather loop runs
// in chunks of 16: 16 broadcast ds_reads -> 16 independent coalesced 256B
// global gathers in flight -> accumulate. Chunked (NOT fully unrolled) to
// keep VGPR use bounded and avoid the R2 scratch-spill disaster.
__global__ __launch_bounds__(256, 8) void fm_layer_kernel(
    const float* __restrict__ inputs,      // (B, 300)
    const float* __restrict__ w_one_hot,   // (1e6, 1)
    const float* __restrict__ w_numeric,   // (100, 1)
    const float* __restrict__ v_one_hot,   // (1e6, 64)
    const float* __restrict__ v_numeric,   // (100, 64)
    const float* __restrict__ bias,        // (1,)
    float* __restrict__ out)               // (B, 1)
{
    __shared__ int   s_idx[WAVES_PER_BLOCK][FEATURE_NUM];
    __shared__ float s_num[WAVES_PER_BLOCK][NUMERIC_SIZE];

    const int lane = threadIdx.x & 63;
    const int wave = threadIdx.x >> 6;
    const int row  = blockIdx.x * WAVES_PER_BLOCK + wave;

    const float* in_row = inputs + (size_t)row * IN_STRIDE;

    // coalesced preload of this row's 300 floats; convert indices to int once
    for (int j = lane; j < IN_STRIDE; j += 64) {
        float x = in_row[j];
        if (j < FEATURE_NUM) s_idx[wave][j] = (int)x;
        else                 s_num[wave][j - FEATURE_NUM] = x;
    }
    __syncthreads();

    float fs = 0.f, fss = 0.f, first = 0.f;

    // ---- second-order one-hot gathers: 12 chunks of 16 + tail of 8 ----
    #pragma unroll 1
    for (int c = 0; c < 192; c += 16) {
        int   idx[16];
        float v[16];
        #pragma unroll
        for (int s = 0; s < 16; ++s) idx[s] = s_idx[wave][c + s];   // broadcast
        #pragma unroll
        for (int s = 0; s < 16; ++s) v[s] = v_one_hot[(size_t)idx[s] * EMBED + lane];
        #pragma unroll
        for (int s = 0; s < 16; ++s) { fs += v[s]; fss += v[s] * v[s]; }
    }
    {   // tail: features 192..199
        int idx[8]; float v[8];
        #pragma unroll
        for (int s = 0; s < 8; ++s) idx[s] = s_idx[wave][192 + s];
        #pragma unroll
        for (int s = 0; s < 8; ++s) v[s] = v_one_hot[(size_t)idx[s] * EMBED + lane];
        #pragma unroll
        for (int s = 0; s < 8; ++s) { fs += v[s]; fss += v[s] * v[s]; }
    }

    // ---- second-order numeric part (v_numeric: 25.6 KB, L2-resident) ----
    #pragma unroll 1
    for (int j = 0; j < NUMERIC_SIZE; j += 10) {
        #pragma unroll
        for (int s = 0; s < 10; ++s) {
            float x  = s_num[wave][j + s];
            float v  = v_numeric[(j + s) * EMBED + lane];
            float nv = x * v;
            fs += nv; fss += nv * nv;
        }
    }

    // ---- first-order: distribute the 200 w_one_hot gathers over lanes ----
    #pragma unroll
    for (int k = 0; k < 4; ++k) {
        int j = lane + 64 * k;
        if (j < FEATURE_NUM) first += w_one_hot[s_idx[wave][j]];
    }
    #pragma unroll
    for (int k = 0; k < 2; ++k) {
        int j = lane + 64 * k;
        if (j < NUMERIC_SIZE) first += s_num[wave][j] * w_numeric[j];
    }

    // per-lane partial: first-order partial + FM identity term for e=lane
    float partial = first + 0.5f * (fs * fs - fss);

    // wave64 reduction
    #pragma unroll
    for (int off = 32; off > 0; off >>= 1)
        partial += __shfl_down(partial, off, 64);

    if (lane == 0) out[row] = partial + bias[0];
}

extern "C" void kernel_launch(void* const* d_in, const int* in_sizes, int n_in,
                              void* d_out, int out_size, void* d_ws, size_t ws_size,
                              hipStream_t stream) {
    const float* inputs    = (const float*)d_in[0];
    const float* w_one_hot = (const float*)d_in[1];
    const float* w_numeric = (const float*)d_in[2];
    const float* v_one_hot = (const float*)d_in[3];
    const float* v_numeric = (const float*)d_in[4];
    const float* bias      = (const float*)d_in[5];
    float* out = (float*)d_out;

    dim3 grid(BATCH / WAVES_PER_BLOCK);
    dim3 block(256);
    fm_layer_kernel<<<grid, block, 0, stream>>>(
        inputs, w_one_hot, w_numeric, v_one_hot, v_numeric, bias, out);
}

// Round 4
// 370.602 us; speedup vs baseline: 1.7407x; 1.0116x over previous
//
#include <hip/hip_runtime.h>

#define BATCH 8192
#define FEATURE_NUM 200
#define NUMERIC_SIZE 100
#define IN_STRIDE (FEATURE_NUM + NUMERIC_SIZE)  // 300
#define EMBED 64
#define WAVES_PER_BLOCK 4
#define CHUNK 8                                  // 200 = 25 chunks of 8

// One wave (64 lanes) per batch row; lane = embedding dim e.
// Row inputs staged once in LDS. Second-order gather loop is software-
// pipelined with two alternating 8-deep register buffers so each wave keeps
// 8-16 gathers in flight continuously (R3 drained vmcnt to 0 every chunk).
// First-order gathers issue early so their latency hides under the loop.
// VGPR kept under 64 so 8 waves/SIMD residency holds (8192 waves == device
// capacity; losing residency adds a second-round tail).

__device__ __forceinline__ void load8(const float* __restrict__ v_one_hot,
                                      const int* sidx, int c, int lane,
                                      float vv[CHUNK]) {
    #pragma unroll
    for (int s = 0; s < CHUNK; ++s) {
        int idx = sidx[c + s];                    // wave-uniform LDS broadcast
        vv[s] = v_one_hot[idx * EMBED + lane];    // coalesced 256B row read
    }
}

__device__ __forceinline__ void accum8(const float vv[CHUNK],
                                       float& fs, float& fss) {
    #pragma unroll
    for (int s = 0; s < CHUNK; ++s) { fs += vv[s]; fss += vv[s] * vv[s]; }
}

__global__ __launch_bounds__(256, 8) void fm_layer_kernel(
    const float* __restrict__ inputs,      // (B, 300)
    const float* __restrict__ w_one_hot,   // (1e6, 1)
    const float* __restrict__ w_numeric,   // (100, 1)
    const float* __restrict__ v_one_hot,   // (1e6, 64)
    const float* __restrict__ v_numeric,   // (100, 64)
    const float* __restrict__ bias,        // (1,)
    float* __restrict__ out)               // (B, 1)
{
    __shared__ int   s_idx[WAVES_PER_BLOCK][FEATURE_NUM];
    __shared__ float s_num[WAVES_PER_BLOCK][NUMERIC_SIZE];

    const int lane = threadIdx.x & 63;
    const int wave = threadIdx.x >> 6;
    const int row  = blockIdx.x * WAVES_PER_BLOCK + wave;

    const float* in_row = inputs + (size_t)row * IN_STRIDE;

    // coalesced preload of this row's 300 floats; convert indices to int once
    for (int j = lane; j < IN_STRIDE; j += 64) {
        float x = in_row[j];
        if (j < FEATURE_NUM) s_idx[wave][j] = (int)x;
        else                 s_num[wave][j - FEATURE_NUM] = x;
    }
    __syncthreads();

    const int* sidx = s_idx[wave];
    const float* snum = s_num[wave];

    // ---- first-order gathers: issue EARLY, consume at the end ----
    float w0 = w_one_hot[sidx[lane]];
    float w1 = w_one_hot[sidx[lane + 64]];
    float w2 = w_one_hot[sidx[lane + 128]];
    float w3 = w_one_hot[sidx[192 + (lane & 7)]];   // only lanes 0-7 count

    float fs = 0.f, fss = 0.f;

    // ---- pipelined second-order one-hot gathers: 25 chunks of 8 ----
    float va[CHUNK], vb[CHUNK];
    load8(v_one_hot, sidx, 0, lane, va);            // prologue: chunk 0

    // ---- numeric second-order (v_numeric: 25.6 KB, L1-resident after warmup)
    // placed here so its VALU work overlaps chunk-0 gather latency
    #pragma unroll 1
    for (int j = 0; j < NUMERIC_SIZE; j += 10) {
        #pragma unroll
        for (int s = 0; s < 10; ++s) {
            float x  = snum[j + s];
            float v  = v_numeric[(j + s) * EMBED + lane];
            float nv = x * v;
            fs += nv; fss += nv * nv;
        }
    }

    // main pipeline: chunks 1..24 (pairs), never draining vmcnt to 0
    #pragma unroll 1
    for (int k = 0; k < 12; ++k) {
        load8(v_one_hot, sidx, (2 * k + 1) * CHUNK, lane, vb);
        accum8(va, fs, fss);                         // waits vmcnt(8), vb flies
        load8(v_one_hot, sidx, (2 * k + 2) * CHUNK, lane, va);
        accum8(vb, fs, fss);                         // waits vmcnt(8), va flies
    }
    accum8(va, fs, fss);                             // epilogue: chunk 24

    // ---- first-order combine ----
    float first = w0 + w1 + w2 + ((lane < 8) ? w3 : 0.f);
    first += snum[lane] * w_numeric[lane];
    if (lane < NUMERIC_SIZE - 64) first += snum[lane + 64] * w_numeric[lane + 64];

    // per-lane partial: first-order partial + FM identity term for e=lane
    float partial = first + 0.5f * (fs * fs - fss);

    // wave64 reduction
    #pragma unroll
    for (int off = 32; off > 0; off >>= 1)
        partial += __shfl_down(partial, off, 64);

    if (lane == 0) out[row] = partial + bias[0];
}

extern "C" void kernel_launch(void* const* d_in, const int* in_sizes, int n_in,
                              void* d_out, int out_size, void* d_ws, size_t ws_size,
                              hipStream_t stream) {
    const float* inputs    = (const float*)d_in[0];
    const float* w_one_hot = (const float*)d_in[1];
    const float* w_numeric = (const float*)d_in[2];
    const float* v_one_hot = (const float*)d_in[3];
    const float* v_numeric = (const float*)d_in[4];
    const float* bias      = (const float*)d_in[5];
    float* out = (float*)d_out;

    dim3 grid(BATCH / WAVES_PER_BLOCK);
    dim3 block(256);
    fm_layer_kernel<<<grid, block, 0, stream>>>(
        inputs, w_one_hot, w_numeric, v_one_hot, v_numeric, bias, out);
}